// Round 1
// baseline (671.350 us; speedup 1.0000x reference)
//
#include <hip/hip_runtime.h>
#include <hip/hip_bf16.h>
#include <cstdint>
#include <cstddef>

typedef __attribute__((ext_vector_type(4))) float  f32x4;
typedef __attribute__((ext_vector_type(8))) __bf16 bf16x8;
typedef __attribute__((ext_vector_type(4))) __bf16 bf16x4;

#define DEV __device__ __forceinline__

DEV void gload_lds16(const void* g, void* l) {
  __builtin_amdgcn_global_load_lds(
      (const __attribute__((address_space(1))) void*)g,
      (__attribute__((address_space(3))) void*)l, 16, 0, 0);
}

DEV float wave16_max(float v) {
#pragma unroll
  for (int s = 1; s < 16; s <<= 1) v = fmaxf(v, __shfl_xor(v, s, 64));
  return v;
}
DEV float wave16_sum(float v) {
#pragma unroll
  for (int s = 1; s < 16; s <<= 1) v += __shfl_xor(v, s, 64);
  return v;
}

// ---------------------------------------------------------------- convert x
__global__ __launch_bounds__(256) void cvt_f32_bf16(
    const float* __restrict__ in, __bf16* __restrict__ out, int n4) {
  int i = blockIdx.x * 256 + threadIdx.x;
  if (i < n4) {
    f32x4 v = ((const f32x4*)in)[i];
    ((bf16x4*)out)[i] = __builtin_convertvector(v, bf16x4);
  }
}

// ------------------------------------------------- transpose fp32 -> bf16^T
// in: R x C (fp32), out: C x R (bf16). R, C multiples of 32.
__global__ void transpose_cvt(const float* __restrict__ in,
                              __bf16* __restrict__ out, int R, int C) {
  __shared__ float tile[32][33];
  int c0 = blockIdx.x * 32, r0 = blockIdx.y * 32;
  int tx = threadIdx.x, ty = threadIdx.y;
#pragma unroll
  for (int i = ty; i < 32; i += 8)
    tile[i][tx] = in[(size_t)(r0 + i) * C + c0 + tx];
  __syncthreads();
#pragma unroll
  for (int i = ty; i < 32; i += 8)
    out[(size_t)(c0 + i) * R + r0 + tx] = (__bf16)tile[tx][i];
}

// --------------------------------------------- big GEMM: C = A @ BT^T +bias
// A: M x K bf16, BT: N x K bf16, 128x128 tile, BK=64, 4 waves (m97 structure)
template <int RELU, int OUT_BF16>
__global__ __launch_bounds__(256) void gemm128(
    const __bf16* __restrict__ A, const __bf16* __restrict__ BT,
    const float* __restrict__ bias, void* __restrict__ Cout,
    int M, int N, int K) {
  __shared__ __bf16 As[128 * 64];
  __shared__ __bf16 Bs[128 * 64];
  const int nbc = N >> 7;
  const int bid = blockIdx.x;
  const int br = bid / nbc, bc = bid - br * nbc;
  const int t = threadIdx.x;
  const int w = t >> 6, l = t & 63;
  const int wr = w >> 1, wc = w & 1;
  const int lr = l & 15, lg = l >> 4;

  f32x4 acc[4][4];
  const f32x4 z = {0.f, 0.f, 0.f, 0.f};
#pragma unroll
  for (int m = 0; m < 4; ++m)
#pragma unroll
    for (int n = 0; n < 4; ++n) acc[m][n] = z;

  const __bf16* gA = A + (size_t)(br * 128 + (t >> 3)) * K + (t & 7) * 8;
  const __bf16* gB = BT + (size_t)(bc * 128 + (t >> 3)) * K + (t & 7) * 8;
  char* lA = (char*)As + t * 16;
  char* lB = (char*)Bs + t * 16;

  for (int kt = 0; kt < K; kt += 64) {
    __syncthreads();
#pragma unroll
    for (int r = 0; r < 4; ++r) {
      gload_lds16(gA + (size_t)r * 32 * K + kt, lA + r * 4096);
      gload_lds16(gB + (size_t)r * 32 * K + kt, lB + r * 4096);
    }
    __syncthreads();
#pragma unroll
    for (int kk = 0; kk < 2; ++kk) {
      bf16x8 af[4], bf[4];
#pragma unroll
      for (int m = 0; m < 4; ++m)
        af[m] = *(const bf16x8*)(As + (wr * 64 + m * 16 + lr) * 64 + kk * 32 + lg * 8);
#pragma unroll
      for (int n = 0; n < 4; ++n)
        bf[n] = *(const bf16x8*)(Bs + (wc * 64 + n * 16 + lr) * 64 + kk * 32 + lg * 8);
#pragma unroll
      for (int m = 0; m < 4; ++m)
#pragma unroll
        for (int n = 0; n < 4; ++n)
          acc[m][n] = __builtin_amdgcn_mfma_f32_16x16x32_bf16(af[m], bf[n], acc[m][n], 0, 0, 0);
    }
  }

#pragma unroll
  for (int n = 0; n < 4; ++n) {
    int col = bc * 128 + wc * 64 + n * 16 + lr;
    float bv = bias[col];
#pragma unroll
    for (int m = 0; m < 4; ++m) {
      int row0 = br * 128 + wr * 64 + m * 16 + lg * 4;
#pragma unroll
      for (int j = 0; j < 4; ++j) {
        float v = acc[m][n][j] + bv;
        if (RELU) v = v > 0.f ? v : 0.f;
        size_t off = (size_t)(row0 + j) * N + col;
        if (OUT_BF16) ((__bf16*)Cout)[off] = (__bf16)v;
        else          ((float*)Cout)[off] = v;
      }
    }
  }
}

// ---------------------- logits = H @ w2T^T + b2, softmax over 32 -> P (bf16)
__global__ __launch_bounds__(256) void enc2_softmax(
    const __bf16* __restrict__ H, const __bf16* __restrict__ W2T,  // 32 x K
    const float* __restrict__ b2, __bf16* __restrict__ P, int K) {
  __shared__ __bf16 As[128 * 64];
  __shared__ __bf16 Bs[32 * 64];
  const int br = blockIdx.x;
  const int t = threadIdx.x;
  const int w = t >> 6, l = t & 63;
  const int lr = l & 15, lg = l >> 4;

  f32x4 acc[2][2];
  const f32x4 z = {0.f, 0.f, 0.f, 0.f};
#pragma unroll
  for (int m = 0; m < 2; ++m)
#pragma unroll
    for (int n = 0; n < 2; ++n) acc[m][n] = z;

  const __bf16* gA = H + (size_t)(br * 128 + (t >> 3)) * K + (t & 7) * 8;
  const __bf16* gB = W2T + (size_t)(t >> 3) * K + (t & 7) * 8;
  char* lA = (char*)As + t * 16;
  char* lB = (char*)Bs + t * 16;

  for (int kt = 0; kt < K; kt += 64) {
    __syncthreads();
#pragma unroll
    for (int r = 0; r < 4; ++r) gload_lds16(gA + (size_t)r * 32 * K + kt, lA + r * 4096);
    gload_lds16(gB + kt, lB);
    __syncthreads();
#pragma unroll
    for (int kk = 0; kk < 2; ++kk) {
      bf16x8 af[2], bf[2];
#pragma unroll
      for (int m = 0; m < 2; ++m)
        af[m] = *(const bf16x8*)(As + (w * 32 + m * 16 + lr) * 64 + kk * 32 + lg * 8);
#pragma unroll
      for (int n = 0; n < 2; ++n)
        bf[n] = *(const bf16x8*)(Bs + (n * 16 + lr) * 64 + kk * 32 + lg * 8);
#pragma unroll
      for (int m = 0; m < 2; ++m)
#pragma unroll
        for (int n = 0; n < 2; ++n)
          acc[m][n] = __builtin_amdgcn_mfma_f32_16x16x32_bf16(af[m], bf[n], acc[m][n], 0, 0, 0);
    }
  }

  float b2lo = b2[lr], b2hi = b2[16 + lr];
#pragma unroll
  for (int m = 0; m < 2; ++m) {
#pragma unroll
    for (int j = 0; j < 4; ++j) {
      float c0 = acc[m][0][j] + b2lo;
      float c1 = acc[m][1][j] + b2hi;
      float mx = wave16_max(fmaxf(c0, c1));
      float e0 = __expf(c0 - mx), e1 = __expf(c1 - mx);
      float sm = wave16_sum(e0 + e1);
      float inv = 1.f / sm;
      int row = br * 128 + w * 32 + m * 16 + lg * 4 + j;
      P[(size_t)row * 32 + lr]      = (__bf16)(e0 * inv);
      P[(size_t)row * 32 + 16 + lr] = (__bf16)(e1 * inv);
    }
  }
}

// ----------------------------- TH = relu(cur @ tr_w1 + b1)   (Mout x 64)
__global__ __launch_bounds__(256) void trans1(
    const __bf16* __restrict__ P, const __bf16* __restrict__ W1T,  // 64 x 32
    const float* __restrict__ b1, __bf16* __restrict__ TH, int Mout) {
  const int t = threadIdx.x;
  const int w = t >> 6, l = t & 63;
  const int lr = l & 15, lg = l >> 4;
  const int rowbase = blockIdx.x * 128 + w * 32;

  f32x4 acc[2][4];
  const f32x4 z = {0.f, 0.f, 0.f, 0.f};
#pragma unroll
  for (int m = 0; m < 2; ++m)
#pragma unroll
    for (int n = 0; n < 4; ++n) acc[m][n] = z;

  bf16x8 af[2], bf[4];
#pragma unroll
  for (int m = 0; m < 2; ++m) {
    int orow = rowbase + m * 16 + lr;
    if (orow > Mout - 1) orow = Mout - 1;
    int q = orow / 1023;
    int prow = q * 1024 + (orow - q * 1023);
    af[m] = *(const bf16x8*)(P + (size_t)prow * 32 + lg * 8);
  }
#pragma unroll
  for (int n = 0; n < 4; ++n)
    bf[n] = *(const bf16x8*)(W1T + (n * 16 + lr) * 32 + lg * 8);
#pragma unroll
  for (int m = 0; m < 2; ++m)
#pragma unroll
    for (int n = 0; n < 4; ++n)
      acc[m][n] = __builtin_amdgcn_mfma_f32_16x16x32_bf16(af[m], bf[n], acc[m][n], 0, 0, 0);

#pragma unroll
  for (int n = 0; n < 4; ++n) {
    int col = n * 16 + lr;
    float bv = b1[col];
#pragma unroll
    for (int m = 0; m < 2; ++m) {
      int row0 = rowbase + m * 16 + lg * 4;
#pragma unroll
      for (int j = 0; j < 4; ++j) {
        int row = row0 + j;
        if (row < Mout) {
          float v = acc[m][n][j] + bv;
          v = v > 0.f ? v : 0.f;
          TH[(size_t)row * 64 + col] = (__bf16)v;
        }
      }
    }
  }
}

// ----------------- TL = TH @ tr_w2 + b2, softmax over 32-groups -> out1 fp32
__global__ __launch_bounds__(256) void trans2_softmax(
    const __bf16* __restrict__ TH, const __bf16* __restrict__ W2T,  // 1024 x 64
    const float* __restrict__ b2, float* __restrict__ out1, int Mout) {
  const int bid = blockIdx.x;
  const int br = bid >> 3, bc = bid & 7;
  const int t = threadIdx.x;
  const int w = t >> 6, l = t & 63;
  const int wr = w >> 1, wc = w & 1;
  const int lr = l & 15, lg = l >> 4;

  f32x4 acc[4][4];
  const f32x4 z = {0.f, 0.f, 0.f, 0.f};
#pragma unroll
  for (int m = 0; m < 4; ++m)
#pragma unroll
    for (int n = 0; n < 4; ++n) acc[m][n] = z;

#pragma unroll
  for (int ks = 0; ks < 2; ++ks) {
    bf16x8 af[4], bf[4];
#pragma unroll
    for (int m = 0; m < 4; ++m) {
      int ar = br * 128 + wr * 64 + m * 16 + lr;
      if (ar > Mout - 1) ar = Mout - 1;
      af[m] = *(const bf16x8*)(TH + (size_t)ar * 64 + ks * 32 + lg * 8);
    }
#pragma unroll
    for (int n = 0; n < 4; ++n) {
      int bn = bc * 128 + wc * 64 + n * 16 + lr;
      bf[n] = *(const bf16x8*)(W2T + (size_t)bn * 64 + ks * 32 + lg * 8);
    }
#pragma unroll
    for (int m = 0; m < 4; ++m)
#pragma unroll
      for (int n = 0; n < 4; ++n)
        acc[m][n] = __builtin_amdgcn_mfma_f32_16x16x32_bf16(af[m], bf[n], acc[m][n], 0, 0, 0);
  }

#pragma unroll
  for (int m = 0; m < 4; ++m) {
    int row0 = br * 128 + wr * 64 + m * 16 + lg * 4;
#pragma unroll
    for (int j = 0; j < 4; ++j) {
      int r = row0 + j;
      bool valid = r < Mout;
#pragma unroll
      for (int g = 0; g < 2; ++g) {
        int c0 = bc * 128 + wc * 64 + g * 32 + lr;
        int c1 = c0 + 16;
        float v0 = acc[m][2 * g][j] + b2[c0];
        float v1 = acc[m][2 * g + 1][j] + b2[c1];
        float mx = wave16_max(fmaxf(v0, v1));
        float e0 = __expf(v0 - mx), e1 = __expf(v1 - mx);
        float sm = wave16_sum(e0 + e1);
        float inv = 1.f / sm;
        if (valid) {
          out1[(size_t)r * 1024 + c0] = e0 * inv;
          out1[(size_t)r * 1024 + c1] = e1 * inv;
        }
      }
    }
  }
}

// --------------------------- DH = relu(P @ dec_w1 + b1)  (32768 x 1024 bf16)
__global__ __launch_bounds__(256) void dec1(
    const __bf16* __restrict__ P, const __bf16* __restrict__ W1T,  // 1024 x 32
    const float* __restrict__ b1, __bf16* __restrict__ DH) {
  const int bid = blockIdx.x;
  const int br = bid >> 3, bc = bid & 7;
  const int t = threadIdx.x;
  const int w = t >> 6, l = t & 63;
  const int wr = w >> 1, wc = w & 1;
  const int lr = l & 15, lg = l >> 4;

  f32x4 acc[4][4];
  const f32x4 z = {0.f, 0.f, 0.f, 0.f};
#pragma unroll
  for (int m = 0; m < 4; ++m)
#pragma unroll
    for (int n = 0; n < 4; ++n) acc[m][n] = z;

  bf16x8 af[4], bf[4];
#pragma unroll
  for (int m = 0; m < 4; ++m)
    af[m] = *(const bf16x8*)(P + (size_t)(br * 128 + wr * 64 + m * 16 + lr) * 32 + lg * 8);
#pragma unroll
  for (int n = 0; n < 4; ++n)
    bf[n] = *(const bf16x8*)(W1T + (size_t)(bc * 128 + wc * 64 + n * 16 + lr) * 32 + lg * 8);
#pragma unroll
  for (int m = 0; m < 4; ++m)
#pragma unroll
    for (int n = 0; n < 4; ++n)
      acc[m][n] = __builtin_amdgcn_mfma_f32_16x16x32_bf16(af[m], bf[n], acc[m][n], 0, 0, 0);

#pragma unroll
  for (int n = 0; n < 4; ++n) {
    int col = bc * 128 + wc * 64 + n * 16 + lr;
    float bv = b1[col];
#pragma unroll
    for (int m = 0; m < 4; ++m) {
      int row0 = br * 128 + wr * 64 + m * 16 + lg * 4;
#pragma unroll
      for (int j = 0; j < 4; ++j) {
        float v = acc[m][n][j] + bv;
        v = v > 0.f ? v : 0.f;
        DH[(size_t)(row0 + j) * 1024 + col] = (__bf16)v;
      }
    }
  }
}

extern "C" void kernel_launch(void* const* d_in, const int* in_sizes, int n_in,
                              void* d_out, int out_size, void* d_ws, size_t ws_size,
                              hipStream_t stream) {
  const float* x      = (const float*)d_in[0];
  const float* enc_w1 = (const float*)d_in[1];
  const float* enc_b1 = (const float*)d_in[2];
  const float* enc_w2 = (const float*)d_in[3];
  const float* enc_b2 = (const float*)d_in[4];
  const float* tr_w1  = (const float*)d_in[5];
  const float* tr_b1  = (const float*)d_in[6];
  const float* tr_w2  = (const float*)d_in[7];
  const float* tr_b2  = (const float*)d_in[8];
  const float* dec_w1 = (const float*)d_in[9];
  const float* dec_b1 = (const float*)d_in[10];
  const float* dec_w2 = (const float*)d_in[11];
  const float* dec_b2 = (const float*)d_in[12];

  char* ws = (char*)d_ws;
  __bf16* Xbf  = (__bf16*)(ws);                 // 67108864 B (reused for DH)
  __bf16* P    = (__bf16*)(ws + 67108864);      // 2 MB
  __bf16* TH   = (__bf16*)(ws + 69206016);      // 4 MB
  __bf16* w1T  = (__bf16*)(ws + 73400320);      // enc_w1^T  1024x1024
  __bf16* w2T  = (__bf16*)(ws + 75497472);      // enc_w2^T  32x1024
  __bf16* tw1T = (__bf16*)(ws + 75563008);      // tr_w1^T   64x32
  __bf16* tw2T = (__bf16*)(ws + 75567104);      // tr_w2^T   1024x64
  __bf16* dw1T = (__bf16*)(ws + 75698176);      // dec_w1^T  1024x32
  __bf16* dw2T = (__bf16*)(ws + 75763712);      // dec_w2^T  1024x1024
  __bf16* DH   = Xbf;

  float* out0 = (float*)d_out;
  float* out1 = out0 + 33554432;
  __bf16* Hbf = (__bf16*)out1;  // 64 MB of H inside the 128 MB out1 region

  // convert / transpose weights+input to bf16
  cvt_f32_bf16<<<32768, 256, 0, stream>>>(x, Xbf, 8388608);
  transpose_cvt<<<dim3(32, 32), dim3(32, 8), 0, stream>>>(enc_w1, w1T, 1024, 1024);
  transpose_cvt<<<dim3(1, 32),  dim3(32, 8), 0, stream>>>(enc_w2, w2T, 1024, 32);
  transpose_cvt<<<dim3(2, 1),   dim3(32, 8), 0, stream>>>(tr_w1,  tw1T, 32, 64);
  transpose_cvt<<<dim3(32, 2),  dim3(32, 8), 0, stream>>>(tr_w2,  tw2T, 64, 1024);
  transpose_cvt<<<dim3(32, 1),  dim3(32, 8), 0, stream>>>(dec_w1, dw1T, 32, 1024);
  transpose_cvt<<<dim3(32, 32), dim3(32, 8), 0, stream>>>(dec_w2, dw2T, 1024, 1024);

  // h = relu(x @ enc_w1 + enc_b1)
  gemm128<1, 1><<<2048, 256, 0, stream>>>(Xbf, w1T, enc_b1, Hbf, 32768, 1024, 1024);
  // state_probs
  enc2_softmax<<<256, 256, 0, stream>>>(Hbf, w2T, enc_b2, P, 1024);
  // transition path
  trans1<<<256, 256, 0, stream>>>(P, tw1T, tr_b1, TH, 32736);
  trans2_softmax<<<2048, 256, 0, stream>>>(TH, tw2T, tr_b2, out1, 32736);
  // decoder path
  dec1<<<2048, 256, 0, stream>>>(P, dw1T, dec_b1, DH);
  gemm128<0, 0><<<2048, 256, 0, stream>>>(DH, dw2T, dec_b2, out0, 32768, 1024, 1024);
}

// Round 2
// 619.641 us; speedup vs baseline: 1.0835x; 1.0835x over previous
//
#include <hip/hip_runtime.h>
#include <hip/hip_bf16.h>
#include <cstdint>
#include <cstddef>

typedef __attribute__((ext_vector_type(4))) float  f32x4;
typedef __attribute__((ext_vector_type(8))) __bf16 bf16x8;
typedef __attribute__((ext_vector_type(4))) __bf16 bf16x4;

#define DEV __device__ __forceinline__

DEV void gload_lds16(const void* g, void* l) {
  __builtin_amdgcn_global_load_lds(
      (const __attribute__((address_space(1))) void*)g,
      (__attribute__((address_space(3))) void*)l, 16, 0, 0);
}

DEV float wave16_max(float v) {
#pragma unroll
  for (int s = 1; s < 16; s <<= 1) v = fmaxf(v, __shfl_xor(v, s, 64));
  return v;
}
DEV float wave16_sum(float v) {
#pragma unroll
  for (int s = 1; s < 16; s <<= 1) v += __shfl_xor(v, s, 64);
  return v;
}

// sync macros for the 8-phase schedule (raw s_barrier; NO __syncthreads —
// __syncthreads drains vmcnt(0) and kills the counted pipeline)
#define SBAR()  do { __builtin_amdgcn_sched_barrier(0); __builtin_amdgcn_s_barrier(); __builtin_amdgcn_sched_barrier(0); } while (0)
#define LGKM0() do { asm volatile("s_waitcnt lgkmcnt(0)" ::: "memory"); __builtin_amdgcn_sched_barrier(0); } while (0)
#define VMW(n)  do { asm volatile("s_waitcnt vmcnt(" #n ")" ::: "memory"); __builtin_amdgcn_sched_barrier(0); } while (0)

// ---------------------------------------------------------------- convert x
__global__ __launch_bounds__(256) void cvt_f32_bf16(
    const float* __restrict__ in, __bf16* __restrict__ out, int n4) {
  int i = blockIdx.x * 256 + threadIdx.x;
  if (i < n4) {
    f32x4 v = ((const f32x4*)in)[i];
    ((bf16x4*)out)[i] = __builtin_convertvector(v, bf16x4);
  }
}

// ------------------------------------------------- transpose fp32 -> bf16^T
__global__ void transpose_cvt(const float* __restrict__ in,
                              __bf16* __restrict__ out, int R, int C) {
  __shared__ float tile[32][33];
  int c0 = blockIdx.x * 32, r0 = blockIdx.y * 32;
  int tx = threadIdx.x, ty = threadIdx.y;
#pragma unroll
  for (int i = ty; i < 32; i += 8)
    tile[i][tx] = in[(size_t)(r0 + i) * C + c0 + tx];
  __syncthreads();
#pragma unroll
  for (int i = ty; i < 32; i += 8)
    out[(size_t)(c0 + i) * R + r0 + tx] = (__bf16)tile[tx][i];
}

// ===================== 256x256 8-phase GEMM: C = A @ BT^T + bias ==========
// A: M x K bf16 row-major, BT: N x K bf16 row-major. M%256==0, N%256==0,
// K/64 a power of two (K=1024 here). 512 threads = 8 waves (2Mx4N),
// wave tile 128x64, BK=64, LDS 128KB double-buffered, st-swizzled reads
// with inverse-swizzled global sources (global_load_lds writes linearly).
template <int RELU, int OUT_BF16>
__global__ __launch_bounds__(512, 2) void gemm256(
    const __bf16* __restrict__ A, const __bf16* __restrict__ BT,
    const float* __restrict__ bias, void* __restrict__ Cout,
    int M, int N, int K) {
  __shared__ char lds[131072];  // A: [buf]*32768 ; B: 65536 + [buf]*32768

  const int nbc = N >> 8;
  int bid = blockIdx.x;
  const int cpx = gridDim.x >> 3;        // grid % 8 == 0 in our launches
  bid = (bid & 7) * cpx + (bid >> 3);    // XCD-contiguous remap
  const int br = bid / nbc, bc = bid - br * nbc;

  const int t = threadIdx.x;
  const int w = t >> 6, l = t & 63;
  const int wr = w >> 2, wc = w & 3;     // 2 x 4 wave grid
  const int lr = l & 15, lg = l >> 4;

  // ---- staging constants: thread covers 2x16B chunks of each 16KB half ----
  const int q0 = w * 2048 + l * 16;              // chunk0 byte in half-region
  const int r0 = q0 >> 7;                        // row in half (0..127)
  const int lc = (q0 & 127) ^ ((r0 & 7) << 4);   // inverse-swizzled col byte

  const char* gAb = (const char*)A  + ((size_t)(br * 256 + r0) * K) * 2 + lc;
  const char* gBb = (const char*)BT + ((size_t)(bc * 256 + r0) * K) * 2 + lc;
  const size_t rowK8   = (size_t)8   * K * 2;    // chunk1 = +8 rows
  const size_t rowK128 = (size_t)128 * K * 2;    // half hi = +128 rows
  char* ldsp = (char*)lds;
  const int ntm = (K >> 6) - 1;                  // tile-index mask

  f32x4 acc[8][4];
  const f32x4 z = {0.f, 0.f, 0.f, 0.f};
#pragma unroll
  for (int m = 0; m < 8; ++m)
#pragma unroll
    for (int n = 0; n < 4; ++n) acc[m][n] = z;

  bf16x8 af[4][2], bf0[2][2], bf1[2][2];

#define STAGE_A(tile, h, b)                                                  \
  do {                                                                       \
    const char* _s = gAb + (size_t)(((tile) & ntm) << 7) + ((h) ? rowK128 : 0); \
    char* _d = ldsp + (b) * 32768 + (h) * 16384 + q0;                        \
    gload_lds16(_s, _d);                                                     \
    gload_lds16(_s + rowK8, _d + 1024);                                      \
  } while (0)
#define STAGE_B(tile, h, b)                                                  \
  do {                                                                       \
    const char* _s = gBb + (size_t)(((tile) & ntm) << 7) + ((h) ? rowK128 : 0); \
    char* _d = ldsp + 65536 + (b) * 32768 + (h) * 16384 + q0;                \
    gload_lds16(_s, _d);                                                     \
    gload_lds16(_s + rowK8, _d + 1024);                                      \
  } while (0)

#define RD_A(b, m, kk)                                                        \
  (*(const bf16x8*)(ldsp + (b) * 32768 +                                      \
                    (wr * 128 + (m) * 16 + lr) * 128 +                        \
                    (((kk) * 64 + lg * 16) ^ (((wr * 128 + (m) * 16 + lr) & 7) << 4))))
#define RD_B(b, n, kk)                                                        \
  (*(const bf16x8*)(ldsp + 65536 + (b) * 32768 +                              \
                    (wc * 64 + (n) * 16 + lr) * 128 +                         \
                    (((kk) * 64 + lg * 16) ^ (((wc * 64 + (n) * 16 + lr) & 7) << 4))))

  // ---- prologue: tile0 full -> buf0, tile1 B -> buf1 ----
  STAGE_B(0, 0, 0); STAGE_B(0, 1, 0);
  STAGE_A(0, 0, 0); STAGE_A(0, 1, 0);
  STAGE_B(1, 0, 1); STAGE_B(1, 1, 1);
  VMW(4);           // tile0's 8 loads landed; tile1 B may fly
  SBAR();

  const int NI = K >> 7;  // iterations of 2 K-tiles
  for (int i = 0; i < NI; ++i) {
    const int T0 = 2 * i;

    // ---- P1: ds af[m0-3]+bf01 (buf0) | stage A-lo(T0+1)->buf1 | Q(m0-3,n0-1)
#pragma unroll
    for (int m = 0; m < 4; ++m) { af[m][0] = RD_A(0, m, 0); af[m][1] = RD_A(0, m, 1); }
#pragma unroll
    for (int n = 0; n < 2; ++n) { bf0[n][0] = RD_B(0, n, 0); bf0[n][1] = RD_B(0, n, 1); }
    STAGE_A(T0 + 1, 0, 1);
    SBAR(); LGKM0();
    __builtin_amdgcn_s_setprio(1);
#pragma unroll
    for (int m = 0; m < 4; ++m)
#pragma unroll
      for (int n = 0; n < 2; ++n)
#pragma unroll
        for (int kk = 0; kk < 2; ++kk)
          acc[m][n] = __builtin_amdgcn_mfma_f32_16x16x32_bf16(af[m][kk], bf0[n][kk], acc[m][n], 0, 0, 0);
    __builtin_amdgcn_s_setprio(0);
    SBAR();

    // ---- P2: ds bf23 (buf0) | stage A-hi(T0+1)->buf1 | Q(m0-3,n2-3)
#pragma unroll
    for (int n = 0; n < 2; ++n) { bf1[n][0] = RD_B(0, 2 + n, 0); bf1[n][1] = RD_B(0, 2 + n, 1); }
    STAGE_A(T0 + 1, 1, 1);
    SBAR(); LGKM0();
    __builtin_amdgcn_s_setprio(1);
#pragma unroll
    for (int m = 0; m < 4; ++m)
#pragma unroll
      for (int n = 0; n < 2; ++n)
#pragma unroll
        for (int kk = 0; kk < 2; ++kk)
          acc[m][2 + n] = __builtin_amdgcn_mfma_f32_16x16x32_bf16(af[m][kk], bf1[n][kk], acc[m][2 + n], 0, 0, 0);
    __builtin_amdgcn_s_setprio(0);
    SBAR();

    // ---- P3: ds af[m4-7] (buf0) | stage B-lo(T0+2)->buf0 | Q(m4-7,n2-3)
#pragma unroll
    for (int m = 0; m < 4; ++m) { af[m][0] = RD_A(0, 4 + m, 0); af[m][1] = RD_A(0, 4 + m, 1); }
    STAGE_B(T0 + 2, 0, 0);
    SBAR(); LGKM0();
    __builtin_amdgcn_s_setprio(1);
#pragma unroll
    for (int m = 0; m < 4; ++m)
#pragma unroll
      for (int n = 0; n < 2; ++n)
#pragma unroll
        for (int kk = 0; kk < 2; ++kk)
          acc[4 + m][2 + n] = __builtin_amdgcn_mfma_f32_16x16x32_bf16(af[m][kk], bf1[n][kk], acc[4 + m][2 + n], 0, 0, 0);
    __builtin_amdgcn_s_setprio(0);
    SBAR();

    // ---- P4: stage B-hi(T0+2)->buf0 | vmcnt(4) | Q(m4-7,n0-1)
    STAGE_B(T0 + 2, 1, 0);
    VMW(4);
    SBAR();
    __builtin_amdgcn_s_setprio(1);
#pragma unroll
    for (int m = 0; m < 4; ++m)
#pragma unroll
      for (int n = 0; n < 2; ++n)
#pragma unroll
        for (int kk = 0; kk < 2; ++kk)
          acc[4 + m][n] = __builtin_amdgcn_mfma_f32_16x16x32_bf16(af[m][kk], bf0[n][kk], acc[4 + m][n], 0, 0, 0);
    __builtin_amdgcn_s_setprio(0);
    SBAR();

    // ---- P5: ds af[m0-3]+bf01 (buf1) | stage A-lo(T0+2)->buf0 | Q(m0-3,n0-1)
#pragma unroll
    for (int m = 0; m < 4; ++m) { af[m][0] = RD_A(1, m, 0); af[m][1] = RD_A(1, m, 1); }
#pragma unroll
    for (int n = 0; n < 2; ++n) { bf0[n][0] = RD_B(1, n, 0); bf0[n][1] = RD_B(1, n, 1); }
    STAGE_A(T0 + 2, 0, 0);
    SBAR(); LGKM0();
    __builtin_amdgcn_s_setprio(1);
#pragma unroll
    for (int m = 0; m < 4; ++m)
#pragma unroll
      for (int n = 0; n < 2; ++n)
#pragma unroll
        for (int kk = 0; kk < 2; ++kk)
          acc[m][n] = __builtin_amdgcn_mfma_f32_16x16x32_bf16(af[m][kk], bf0[n][kk], acc[m][n], 0, 0, 0);
    __builtin_amdgcn_s_setprio(0);
    SBAR();

    // ---- P6: ds bf23 (buf1) | stage A-hi(T0+2)->buf0 | Q(m0-3,n2-3)
#pragma unroll
    for (int n = 0; n < 2; ++n) { bf1[n][0] = RD_B(1, 2 + n, 0); bf1[n][1] = RD_B(1, 2 + n, 1); }
    STAGE_A(T0 + 2, 1, 0);
    SBAR(); LGKM0();
    __builtin_amdgcn_s_setprio(1);
#pragma unroll
    for (int m = 0; m < 4; ++m)
#pragma unroll
      for (int n = 0; n < 2; ++n)
#pragma unroll
        for (int kk = 0; kk < 2; ++kk)
          acc[m][2 + n] = __builtin_amdgcn_mfma_f32_16x16x32_bf16(af[m][kk], bf1[n][kk], acc[m][2 + n], 0, 0, 0);
    __builtin_amdgcn_s_setprio(0);
    SBAR();

    // ---- P7: ds af[m4-7] (buf1) | stage B-lo(T0+3)->buf1 | Q(m4-7,n2-3)
#pragma unroll
    for (int m = 0; m < 4; ++m) { af[m][0] = RD_A(1, 4 + m, 0); af[m][1] = RD_A(1, 4 + m, 1); }
    STAGE_B(T0 + 3, 0, 1);
    SBAR(); LGKM0();
    __builtin_amdgcn_s_setprio(1);
#pragma unroll
    for (int m = 0; m < 4; ++m)
#pragma unroll
      for (int n = 0; n < 2; ++n)
#pragma unroll
        for (int kk = 0; kk < 2; ++kk)
          acc[4 + m][2 + n] = __builtin_amdgcn_mfma_f32_16x16x32_bf16(af[m][kk], bf1[n][kk], acc[4 + m][2 + n], 0, 0, 0);
    __builtin_amdgcn_s_setprio(0);
    SBAR();

    // ---- P8: stage B-hi(T0+3)->buf1 | vmcnt(4) | Q(m4-7,n0-1)
    STAGE_B(T0 + 3, 1, 1);
    VMW(4);
    SBAR();
    __builtin_amdgcn_s_setprio(1);
#pragma unroll
    for (int m = 0; m < 4; ++m)
#pragma unroll
      for (int n = 0; n < 2; ++n)
#pragma unroll
        for (int kk = 0; kk < 2; ++kk)
          acc[4 + m][n] = __builtin_amdgcn_mfma_f32_16x16x32_bf16(af[m][kk], bf0[n][kk], acc[4 + m][n], 0, 0, 0);
    __builtin_amdgcn_s_setprio(0);
    SBAR();
  }

  asm volatile("s_waitcnt vmcnt(0)" ::: "memory");

  // ---- epilogue ----
#pragma unroll
  for (int n = 0; n < 4; ++n) {
    const int col = bc * 256 + wc * 64 + n * 16 + lr;
    const float bv = bias[col];
#pragma unroll
    for (int m = 0; m < 8; ++m) {
      const int row0 = br * 256 + wr * 128 + m * 16 + lg * 4;
#pragma unroll
      for (int j = 0; j < 4; ++j) {
        float v = acc[m][n][j] + bv;
        if (RELU) v = v > 0.f ? v : 0.f;
        const size_t off = (size_t)(row0 + j) * N + col;
        if (OUT_BF16) ((__bf16*)Cout)[off] = (__bf16)v;
        else          ((float*)Cout)[off] = v;
      }
    }
  }
#undef STAGE_A
#undef STAGE_B
#undef RD_A
#undef RD_B
}

// ---------------------- logits = H @ w2T^T + b2, softmax over 32 -> P (bf16)
__global__ __launch_bounds__(256) void enc2_softmax(
    const __bf16* __restrict__ H, const __bf16* __restrict__ W2T,  // 32 x K
    const float* __restrict__ b2, __bf16* __restrict__ P, int K) {
  __shared__ __bf16 As[128 * 64];
  __shared__ __bf16 Bs[32 * 64];
  const int br = blockIdx.x;
  const int t = threadIdx.x;
  const int w = t >> 6, l = t & 63;
  const int lr = l & 15, lg = l >> 4;

  f32x4 acc[2][2];
  const f32x4 z = {0.f, 0.f, 0.f, 0.f};
#pragma unroll
  for (int m = 0; m < 2; ++m)
#pragma unroll
    for (int n = 0; n < 2; ++n) acc[m][n] = z;

  const __bf16* gA = H + (size_t)(br * 128 + (t >> 3)) * K + (t & 7) * 8;
  const __bf16* gB = W2T + (size_t)(t >> 3) * K + (t & 7) * 8;
  char* lA = (char*)As + t * 16;
  char* lB = (char*)Bs + t * 16;

  for (int kt = 0; kt < K; kt += 64) {
    __syncthreads();
#pragma unroll
    for (int r = 0; r < 4; ++r) gload_lds16(gA + (size_t)r * 32 * K + kt, lA + r * 4096);
    gload_lds16(gB + kt, lB);
    __syncthreads();
#pragma unroll
    for (int kk = 0; kk < 2; ++kk) {
      bf16x8 af[2], bf[2];
#pragma unroll
      for (int m = 0; m < 2; ++m)
        af[m] = *(const bf16x8*)(As + (w * 32 + m * 16 + lr) * 64 + kk * 32 + lg * 8);
#pragma unroll
      for (int n = 0; n < 2; ++n)
        bf[n] = *(const bf16x8*)(Bs + (n * 16 + lr) * 64 + kk * 32 + lg * 8);
#pragma unroll
      for (int m = 0; m < 2; ++m)
#pragma unroll
        for (int n = 0; n < 2; ++n)
          acc[m][n] = __builtin_amdgcn_mfma_f32_16x16x32_bf16(af[m], bf[n], acc[m][n], 0, 0, 0);
    }
  }

  float b2lo = b2[lr], b2hi = b2[16 + lr];
#pragma unroll
  for (int m = 0; m < 2; ++m) {
#pragma unroll
    for (int j = 0; j < 4; ++j) {
      float c0 = acc[m][0][j] + b2lo;
      float c1 = acc[m][1][j] + b2hi;
      float mx = wave16_max(fmaxf(c0, c1));
      float e0 = __expf(c0 - mx), e1 = __expf(c1 - mx);
      float sm = wave16_sum(e0 + e1);
      float inv = 1.f / sm;
      int row = br * 128 + w * 32 + m * 16 + lg * 4 + j;
      P[(size_t)row * 32 + lr]      = (__bf16)(e0 * inv);
      P[(size_t)row * 32 + 16 + lr] = (__bf16)(e1 * inv);
    }
  }
}

// ----------------------------- TH = relu(cur @ tr_w1 + b1)   (Mout x 64)
__global__ __launch_bounds__(256) void trans1(
    const __bf16* __restrict__ P, const __bf16* __restrict__ W1T,  // 64 x 32
    const float* __restrict__ b1, __bf16* __restrict__ TH, int Mout) {
  const int t = threadIdx.x;
  const int w = t >> 6, l = t & 63;
  const int lr = l & 15, lg = l >> 4;
  const int rowbase = blockIdx.x * 128 + w * 32;

  f32x4 acc[2][4];
  const f32x4 z = {0.f, 0.f, 0.f, 0.f};
#pragma unroll
  for (int m = 0; m < 2; ++m)
#pragma unroll
    for (int n = 0; n < 4; ++n) acc[m][n] = z;

  bf16x8 af[2], bf[4];
#pragma unroll
  for (int m = 0; m < 2; ++m) {
    int orow = rowbase + m * 16 + lr;
    if (orow > Mout - 1) orow = Mout - 1;
    int q = orow / 1023;
    int prow = q * 1024 + (orow - q * 1023);
    af[m] = *(const bf16x8*)(P + (size_t)prow * 32 + lg * 8);
  }
#pragma unroll
  for (int n = 0; n < 4; ++n)
    bf[n] = *(const bf16x8*)(W1T + (n * 16 + lr) * 32 + lg * 8);
#pragma unroll
  for (int m = 0; m < 2; ++m)
#pragma unroll
    for (int n = 0; n < 4; ++n)
      acc[m][n] = __builtin_amdgcn_mfma_f32_16x16x32_bf16(af[m], bf[n], acc[m][n], 0, 0, 0);

#pragma unroll
  for (int n = 0; n < 4; ++n) {
    int col = n * 16 + lr;
    float bv = b1[col];
#pragma unroll
    for (int m = 0; m < 2; ++m) {
      int row0 = rowbase + m * 16 + lg * 4;
#pragma unroll
      for (int j = 0; j < 4; ++j) {
        int row = row0 + j;
        if (row < Mout) {
          float v = acc[m][n][j] + bv;
          v = v > 0.f ? v : 0.f;
          TH[(size_t)row * 64 + col] = (__bf16)v;
        }
      }
    }
  }
}

// ----------------- TL = TH @ tr_w2 + b2, softmax over 32-groups -> out1 fp32
__global__ __launch_bounds__(256) void trans2_softmax(
    const __bf16* __restrict__ TH, const __bf16* __restrict__ W2T,  // 1024 x 64
    const float* __restrict__ b2, float* __restrict__ out1, int Mout) {
  const int bid = blockIdx.x;
  const int br = bid >> 3, bc = bid & 7;
  const int t = threadIdx.x;
  const int w = t >> 6, l = t & 63;
  const int wr = w >> 1, wc = w & 1;
  const int lr = l & 15, lg = l >> 4;

  f32x4 acc[4][4];
  const f32x4 z = {0.f, 0.f, 0.f, 0.f};
#pragma unroll
  for (int m = 0; m < 4; ++m)
#pragma unroll
    for (int n = 0; n < 4; ++n) acc[m][n] = z;

#pragma unroll
  for (int ks = 0; ks < 2; ++ks) {
    bf16x8 af[4], bf[4];
#pragma unroll
    for (int m = 0; m < 4; ++m) {
      int ar = br * 128 + wr * 64 + m * 16 + lr;
      if (ar > Mout - 1) ar = Mout - 1;
      af[m] = *(const bf16x8*)(TH + (size_t)ar * 64 + ks * 32 + lg * 8);
    }
#pragma unroll
    for (int n = 0; n < 4; ++n) {
      int bn = bc * 128 + wc * 64 + n * 16 + lr;
      bf[n] = *(const bf16x8*)(W2T + (size_t)bn * 64 + ks * 32 + lg * 8);
    }
#pragma unroll
    for (int m = 0; m < 4; ++m)
#pragma unroll
      for (int n = 0; n < 4; ++n)
        acc[m][n] = __builtin_amdgcn_mfma_f32_16x16x32_bf16(af[m], bf[n], acc[m][n], 0, 0, 0);
  }

#pragma unroll
  for (int m = 0; m < 4; ++m) {
    int row0 = br * 128 + wr * 64 + m * 16 + lg * 4;
#pragma unroll
    for (int j = 0; j < 4; ++j) {
      int r = row0 + j;
      bool valid = r < Mout;
#pragma unroll
      for (int g = 0; g < 2; ++g) {
        int c0 = bc * 128 + wc * 64 + g * 32 + lr;
        int c1 = c0 + 16;
        float v0 = acc[m][2 * g][j] + b2[c0];
        float v1 = acc[m][2 * g + 1][j] + b2[c1];
        float mx = wave16_max(fmaxf(v0, v1));
        float e0 = __expf(v0 - mx), e1 = __expf(v1 - mx);
        float sm = wave16_sum(e0 + e1);
        float inv = 1.f / sm;
        if (valid) {
          out1[(size_t)r * 1024 + c0] = e0 * inv;
          out1[(size_t)r * 1024 + c1] = e1 * inv;
        }
      }
    }
  }
}

// --------------------------- DH = relu(P @ dec_w1 + b1)  (32768 x 1024 bf16)
__global__ __launch_bounds__(256) void dec1(
    const __bf16* __restrict__ P, const __bf16* __restrict__ W1T,  // 1024 x 32
    const float* __restrict__ b1, __bf16* __restrict__ DH) {
  const int bid = blockIdx.x;
  const int br = bid >> 3, bc = bid & 7;
  const int t = threadIdx.x;
  const int w = t >> 6, l = t & 63;
  const int wr = w >> 1, wc = w & 1;
  const int lr = l & 15, lg = l >> 4;

  f32x4 acc[4][4];
  const f32x4 z = {0.f, 0.f, 0.f, 0.f};
#pragma unroll
  for (int m = 0; m < 4; ++m)
#pragma unroll
    for (int n = 0; n < 4; ++n) acc[m][n] = z;

  bf16x8 af[4], bf[4];
#pragma unroll
  for (int m = 0; m < 4; ++m)
    af[m] = *(const bf16x8*)(P + (size_t)(br * 128 + wr * 64 + m * 16 + lr) * 32 + lg * 8);
#pragma unroll
  for (int n = 0; n < 4; ++n)
    bf[n] = *(const bf16x8*)(W1T + (size_t)(bc * 128 + wc * 64 + n * 16 + lr) * 32 + lg * 8);
#pragma unroll
  for (int m = 0; m < 4; ++m)
#pragma unroll
    for (int n = 0; n < 4; ++n)
      acc[m][n] = __builtin_amdgcn_mfma_f32_16x16x32_bf16(af[m], bf[n], acc[m][n], 0, 0, 0);

#pragma unroll
  for (int n = 0; n < 4; ++n) {
    int col = bc * 128 + wc * 64 + n * 16 + lr;
    float bv = b1[col];
#pragma unroll
    for (int m = 0; m < 4; ++m) {
      int row0 = br * 128 + wr * 64 + m * 16 + lg * 4;
#pragma unroll
      for (int j = 0; j < 4; ++j) {
        float v = acc[m][n][j] + bv;
        v = v > 0.f ? v : 0.f;
        DH[(size_t)(row0 + j) * 1024 + col] = (__bf16)v;
      }
    }
  }
}

extern "C" void kernel_launch(void* const* d_in, const int* in_sizes, int n_in,
                              void* d_out, int out_size, void* d_ws, size_t ws_size,
                              hipStream_t stream) {
  const float* x      = (const float*)d_in[0];
  const float* enc_w1 = (const float*)d_in[1];
  const float* enc_b1 = (const float*)d_in[2];
  const float* enc_w2 = (const float*)d_in[3];
  const float* enc_b2 = (const float*)d_in[4];
  const float* tr_w1  = (const float*)d_in[5];
  const float* tr_b1  = (const float*)d_in[6];
  const float* tr_w2  = (const float*)d_in[7];
  const float* tr_b2  = (const float*)d_in[8];
  const float* dec_w1 = (const float*)d_in[9];
  const float* dec_b1 = (const float*)d_in[10];
  const float* dec_w2 = (const float*)d_in[11];
  const float* dec_b2 = (const float*)d_in[12];

  char* ws = (char*)d_ws;
  __bf16* Xbf  = (__bf16*)(ws);                 // 64 MB (reused for DH)
  __bf16* P    = (__bf16*)(ws + 67108864);      // 2 MB
  __bf16* TH   = (__bf16*)(ws + 69206016);      // 4 MB
  __bf16* w1T  = (__bf16*)(ws + 73400320);      // enc_w1^T  1024x1024
  __bf16* w2T  = (__bf16*)(ws + 75497472);      // enc_w2^T  32x1024
  __bf16* tw1T = (__bf16*)(ws + 75563008);      // tr_w1^T   64x32
  __bf16* tw2T = (__bf16*)(ws + 75567104);      // tr_w2^T   1024x64
  __bf16* dw1T = (__bf16*)(ws + 75698176);      // dec_w1^T  1024x32
  __bf16* dw2T = (__bf16*)(ws + 75763712);      // dec_w2^T  1024x1024
  __bf16* DH   = Xbf;

  float* out0 = (float*)d_out;
  float* out1 = out0 + 33554432;
  __bf16* Hbf = (__bf16*)out1;  // 64 MB of H inside the 128 MB out1 region

  // convert / transpose weights+input to bf16
  cvt_f32_bf16<<<32768, 256, 0, stream>>>(x, Xbf, 8388608);
  transpose_cvt<<<dim3(32, 32), dim3(32, 8), 0, stream>>>(enc_w1, w1T, 1024, 1024);
  transpose_cvt<<<dim3(1, 32),  dim3(32, 8), 0, stream>>>(enc_w2, w2T, 1024, 32);
  transpose_cvt<<<dim3(2, 1),   dim3(32, 8), 0, stream>>>(tr_w1,  tw1T, 32, 64);
  transpose_cvt<<<dim3(32, 2),  dim3(32, 8), 0, stream>>>(tr_w2,  tw2T, 64, 1024);
  transpose_cvt<<<dim3(32, 1),  dim3(32, 8), 0, stream>>>(dec_w1, dw1T, 32, 1024);
  transpose_cvt<<<dim3(32, 32), dim3(32, 8), 0, stream>>>(dec_w2, dw2T, 1024, 1024);

  // h = relu(x @ enc_w1 + enc_b1)   (256^2 8-phase)
  gemm256<1, 1><<<512, 512, 0, stream>>>(Xbf, w1T, enc_b1, Hbf, 32768, 1024, 1024);
  // state_probs
  enc2_softmax<<<256, 256, 0, stream>>>(Hbf, w2T, enc_b2, P, 1024);
  // transition path
  trans1<<<256, 256, 0, stream>>>(P, tw1T, tr_b1, TH, 32736);
  trans2_softmax<<<2048, 256, 0, stream>>>(TH, tw2T, tr_b2, out1, 32736);
  // decoder path
  dec1<<<2048, 256, 0, stream>>>(P, dw1T, dec_b1, DH);
  // markov_out = dh @ dec_w2 + dec_b2   (256^2 8-phase)
  gemm256<0, 0><<<512, 512, 0, stream>>>(DH, dw2T, dec_b2, out0, 32768, 1024, 1024);
}